// Round 1
// baseline (271.181 us; speedup 1.0000x reference)
//
#include <hip/hip_runtime.h>
#include <math.h>

#define SS 1024
#define DD 1024
#define AA 256
#define BB 16

// ---------------------------------------------------------------------------
// Kernel 1: scores[b,s] = tanh(hidden[b,s,:] @ W1 + b1) . v
// grid: (B*S)/16 = 1024 blocks, 256 threads.
// Each block: 16 rows. wave w (4 waves) owns rows 4w..4w+3; lane owns 4 a's.
// ---------------------------------------------------------------------------
__global__ __launch_bounds__(256) void scores_kernel(
    const float* __restrict__ hidden, const float* __restrict__ W1,
    const float* __restrict__ b1, const float* __restrict__ v,
    float* __restrict__ scores)
{
    __shared__ float hbuf[16][256];   // 16 rows x 256-d chunk = 16 KiB
    const int tid  = threadIdx.x;
    const int wave = tid >> 6;
    const int lane = tid & 63;
    const int a4   = lane * 4;
    const int row0 = blockIdx.x * 16;

    float acc[4][4];
    #pragma unroll
    for (int r = 0; r < 4; ++r)
        #pragma unroll
        for (int a = 0; a < 4; ++a) acc[r][a] = 0.f;

    for (int dc = 0; dc < DD; dc += 256) {
        __syncthreads();
        #pragma unroll
        for (int i = 0; i < 16; ++i)
            hbuf[i][tid] = hidden[(size_t)(row0 + i) * DD + dc + tid];
        __syncthreads();

        #pragma unroll 4
        for (int d = 0; d < 256; ++d) {
            const float4 w = *reinterpret_cast<const float4*>(&W1[(size_t)(dc + d) * AA + a4]);
            #pragma unroll
            for (int r = 0; r < 4; ++r) {
                const float h = hbuf[wave * 4 + r][d];   // LDS broadcast
                acc[r][0] += h * w.x;
                acc[r][1] += h * w.y;
                acc[r][2] += h * w.z;
                acc[r][3] += h * w.w;
            }
        }
    }

    const float4 bb = *reinterpret_cast<const float4*>(&b1[a4]);
    const float4 vv = *reinterpret_cast<const float4*>(&v[a4]);
    #pragma unroll
    for (int r = 0; r < 4; ++r) {
        float p = tanhf(acc[r][0] + bb.x) * vv.x
                + tanhf(acc[r][1] + bb.y) * vv.y
                + tanhf(acc[r][2] + bb.z) * vv.z
                + tanhf(acc[r][3] + bb.w) * vv.w;
        #pragma unroll
        for (int off = 32; off > 0; off >>= 1)
            p += __shfl_down(p, off, 64);
        if (lane == 0) scores[row0 + wave * 4 + r] = p;
    }
}

// ---------------------------------------------------------------------------
// Kernel 2: per-batch softmax prep.
// e[b,l] = exp(s - max_b), iv[b,j] = 1/(denom[j] * cnt[j]) per prompt type.
// grid: B blocks, 1024 threads.
// ---------------------------------------------------------------------------
__global__ __launch_bounds__(1024) void prep_kernel(
    const float* __restrict__ scores, const int* __restrict__ pt,
    float* __restrict__ e_out, float* __restrict__ iv_out)
{
    __shared__ float red[1024];
    __shared__ float buf[1024];
    const int b   = blockIdx.x;
    const int tid = threadIdx.x;

    const float s = scores[b * SS + tid];
    red[tid] = s;
    __syncthreads();
    for (int off = 512; off > 0; off >>= 1) {
        if (tid < off) red[tid] = fmaxf(red[tid], red[tid + off]);
        __syncthreads();
    }
    const float m = red[0];
    __syncthreads();

    const float e = expf(s - m);
    e_out[b * SS + tid] = e;

    buf[tid] = e;
    __syncthreads();
    // inclusive Hillis-Steele prefix scan over 1024
    for (int off = 1; off < 1024; off <<= 1) {
        float val = buf[tid];
        if (tid >= off) val += buf[tid - off];
        __syncthreads();
        buf[tid] = val;
        __syncthreads();
    }
    const float P = buf[tid];
    const float Z = buf[1023];

    const int type = pt[b];
    float iv;
    if (type == 0)        iv = 1.f / (P * (float)(tid + 1));               // prefix: l <= j
    else if (type == 1)   iv = 1.f / ((Z - P + e) * (float)(SS - tid));    // postfix: l >= j
    else                  iv = 1.f / ((Z - e) * (float)(SS - 1));          // cloze: l != j
    iv_out[b * SS + tid] = iv;
}

// ---------------------------------------------------------------------------
// Kernel 3: pooled output via per-type scan.
// grid: B * (D/64) = 256 blocks, 256 threads (4 waves x 64 lanes).
// wave w owns l-segment [256w, 256w+256); lane owns one d.
// ---------------------------------------------------------------------------
__global__ __launch_bounds__(256) void pool_kernel(
    const float* __restrict__ hidden, const float* __restrict__ e_in,
    const float* __restrict__ iv_in, const int* __restrict__ pt,
    float* __restrict__ out)
{
    __shared__ float e_s[1024];
    __shared__ float iv_s[1024];
    __shared__ float seg[4][64];

    const int tid    = threadIdx.x;
    const int wave   = tid >> 6;
    const int lane   = tid & 63;
    const int nchunk = DD / 64;
    const int b      = blockIdx.x / nchunk;
    const int d      = (blockIdx.x % nchunk) * 64 + lane;

    #pragma unroll
    for (int i = 0; i < 4; ++i) {
        e_s [tid + i * 256] = e_in [b * SS + tid + i * 256];
        iv_s[tid + i * 256] = iv_in[b * SS + tid + i * 256];
    }
    __syncthreads();

    const float* hb = hidden + (size_t)b * SS * DD + d;
    float*       ob = out    + (size_t)b * SS * DD + d;
    const int l0 = wave * 256;

    // phase 1: per-wave segment sums of e_l * h[l,d]
    float a0 = 0.f, a1 = 0.f, a2 = 0.f, a3 = 0.f;
    #pragma unroll 4
    for (int i = 0; i < 256; i += 4) {
        const int l = l0 + i;
        a0 += e_s[l + 0] * hb[(size_t)(l + 0) * DD];
        a1 += e_s[l + 1] * hb[(size_t)(l + 1) * DD];
        a2 += e_s[l + 2] * hb[(size_t)(l + 2) * DD];
        a3 += e_s[l + 3] * hb[(size_t)(l + 3) * DD];
    }
    seg[wave][lane] = (a0 + a1) + (a2 + a3);
    __syncthreads();

    const int type = pt[b];
    if (type == 0) {                       // prefix: forward scan
        float run = 0.f;
        for (int w = 0; w < wave; ++w) run += seg[w][lane];
        for (int i = 0; i < 256; ++i) {
            const int j = l0 + i;
            run += e_s[j] * hb[(size_t)j * DD];
            ob[(size_t)j * DD] = run * iv_s[j];
        }
    } else if (type == 1) {                // postfix: backward scan
        float run = 0.f;
        for (int w = wave + 1; w < 4; ++w) run += seg[w][lane];
        for (int i = 255; i >= 0; --i) {
            const int j = l0 + i;
            run += e_s[j] * hb[(size_t)j * DD];
            ob[(size_t)j * DD] = run * iv_s[j];
        }
    } else {                               // cloze: total minus self
        const float T = (seg[0][lane] + seg[1][lane]) + (seg[2][lane] + seg[3][lane]);
        for (int i = 0; i < 256; ++i) {
            const int j = l0 + i;
            ob[(size_t)j * DD] = (T - e_s[j] * hb[(size_t)j * DD]) * iv_s[j];
        }
    }
}

// ---------------------------------------------------------------------------
extern "C" void kernel_launch(void* const* d_in, const int* in_sizes, int n_in,
                              void* d_out, int out_size, void* d_ws, size_t ws_size,
                              hipStream_t stream) {
    const float* hidden = (const float*)d_in[0];
    const float* W1     = (const float*)d_in[1];
    const float* b1     = (const float*)d_in[2];
    const float* v      = (const float*)d_in[3];
    const int*   pt     = (const int*)  d_in[4];
    float* out = (float*)d_out;

    float* ws     = (float*)d_ws;
    float* scores = ws;                 // B*S = 16384 f32
    float* e      = ws + BB * SS;       // 16384 f32
    float* iv     = ws + 2 * BB * SS;   // 16384 f32

    scores_kernel<<<(BB * SS) / 16, 256, 0, stream>>>(hidden, W1, b1, v, scores);
    prep_kernel  <<<BB, 1024, 0, stream>>>(scores, pt, e, iv);
    pool_kernel  <<<BB * (DD / 64), 256, 0, stream>>>(hidden, e, iv, pt, out);
}

// Round 3
// 184.938 us; speedup vs baseline: 1.4663x; 1.4663x over previous
//
#include <hip/hip_runtime.h>
#include <math.h>

#define SS 1024
#define DD 1024
#define AA 256
#define BB 16

typedef short short8 __attribute__((ext_vector_type(8)));
typedef short short4v __attribute__((ext_vector_type(4)));
typedef float f32x4 __attribute__((ext_vector_type(4)));

static __device__ __forceinline__ short f2bf(float f) {
    union { float f; unsigned u; } x; x.f = f;
    unsigned r = x.u + 0x7FFFu + ((x.u >> 16) & 1u);   // RNE
    return (short)(r >> 16);
}

// ---------------------------------------------------------------------------
// Kernel 0: pack W1 (f32 [K=1024][N=256]) into bf16 MFMA-fragment order:
//   W1f[((kb*16 + nb)*64 + l)*8 + j] = bf16( W1[kb*32 + (l>>4)*8 + j][nb*16 + (l&15)] )
// Same k-permutation is used for the A fragments, so any bijective k-order is valid.
// grid: 128 blocks x 256 thr (one thread per (kb,nb,l) triple).
// ---------------------------------------------------------------------------
__global__ __launch_bounds__(256) void w1cvt_kernel(
    const float* __restrict__ W1, short* __restrict__ W1f)
{
    const int g  = blockIdx.x * 256 + threadIdx.x;   // 0..32767
    const int l  = g & 63;
    const int nb = (g >> 6) & 15;
    const int kb = g >> 10;
    const int k0 = kb * 32 + ((l >> 4) << 3);
    const int n  = nb * 16 + (l & 15);
    short8 o;
    #pragma unroll
    for (int j = 0; j < 8; ++j) o[j] = f2bf(W1[(size_t)(k0 + j) * AA + n]);
    *reinterpret_cast<short8*>(&W1f[(size_t)g * 8]) = o;
}

// ---------------------------------------------------------------------------
// Kernel 1: scores[b,s] = tanh(hidden @ W1 + b1) . v   via bf16 MFMA.
// grid: 16384/32 = 512 blocks, 256 thr (4 waves). Block: 32 rows x 256 cols.
// Wave w owns cols [64w, 64w+64) (nb = 4w..4w+3), both 16-row m-frags.
// ---------------------------------------------------------------------------
__global__ __launch_bounds__(256) void scores_mfma_kernel(
    const float* __restrict__ hidden, const short* __restrict__ W1f,
    const float* __restrict__ b1, const float* __restrict__ v,
    float* __restrict__ scores)
{
    __shared__ short A_lds[32 * 32];   // [row][k] bf16, 2 KiB
    __shared__ float red[4][32];

    const int tid = threadIdx.x;
    const int w   = tid >> 6;
    const int l   = tid & 63;
    const int row0 = blockIdx.x * 32;

    // staging assignment: thread t -> row t>>3, k-chunk (t&7)*4 (4 f32 = 16B coalesced)
    const int sr = tid >> 3;
    const int sc = (tid & 7) * 4;
    const float* hsrc = hidden + (size_t)(row0 + sr) * DD + sc;

    f32x4 acc[2][4];
    #pragma unroll
    for (int m = 0; m < 2; ++m)
        #pragma unroll
        for (int nb = 0; nb < 4; ++nb)
            #pragma unroll
            for (int r = 0; r < 4; ++r) acc[m][nb][r] = 0.f;

    const int a_off0 = (l & 15) * 32 + ((l >> 4) << 3);
    const short8* w1f8 = reinterpret_cast<const short8*>(W1f);

    for (int kb = 0; kb < 32; ++kb) {
        __syncthreads();
        const float4 hv = *reinterpret_cast<const float4*>(hsrc + kb * 32);
        short4v o;
        o[0] = f2bf(hv.x); o[1] = f2bf(hv.y); o[2] = f2bf(hv.z); o[3] = f2bf(hv.w);
        *reinterpret_cast<short4v*>(&A_lds[sr * 32 + sc]) = o;
        __syncthreads();

        const short8 a0 = *reinterpret_cast<const short8*>(&A_lds[a_off0]);
        const short8 a1 = *reinterpret_cast<const short8*>(&A_lds[a_off0 + 16 * 32]);
        const short8* bp = w1f8 + (size_t)(kb * 16 + w * 4) * 64 + l;
        #pragma unroll
        for (int nb = 0; nb < 4; ++nb) {
            const short8 bfr = bp[nb * 64];
            acc[0][nb] = __builtin_amdgcn_mfma_f32_16x16x32_bf16(a0, bfr, acc[0][nb], 0, 0, 0);
            acc[1][nb] = __builtin_amdgcn_mfma_f32_16x16x32_bf16(a1, bfr, acc[1][nb], 0, 0, 0);
        }
    }

    // epilogue: rowsum over cols of tanh(x + b1) * v
    float b1l[4], vl[4];
    #pragma unroll
    for (int nb = 0; nb < 4; ++nb) {
        const int col = w * 64 + nb * 16 + (l & 15);
        b1l[nb] = b1[col];
        vl[nb]  = v[col];
    }
    #pragma unroll
    for (int m = 0; m < 2; ++m) {
        #pragma unroll
        for (int r = 0; r < 4; ++r) {
            float s = tanhf(acc[m][0][r] + b1l[0]) * vl[0]
                    + tanhf(acc[m][1][r] + b1l[1]) * vl[1]
                    + tanhf(acc[m][2][r] + b1l[2]) * vl[2]
                    + tanhf(acc[m][3][r] + b1l[3]) * vl[3];
            s += __shfl_xor(s, 1, 64);
            s += __shfl_xor(s, 2, 64);
            s += __shfl_xor(s, 4, 64);
            s += __shfl_xor(s, 8, 64);
            if ((l & 15) == 0) red[w][m * 16 + ((l >> 4) << 2) + r] = s;
        }
    }
    __syncthreads();
    if (tid < 32)
        scores[row0 + tid] = red[0][tid] + red[1][tid] + red[2][tid] + red[3][tid];
}

// ---------------------------------------------------------------------------
// Kernel 2: per-batch softmax prep (unchanged).
// ---------------------------------------------------------------------------
__global__ __launch_bounds__(1024) void prep_kernel(
    const float* __restrict__ scores, const int* __restrict__ pt,
    float* __restrict__ e_out, float* __restrict__ iv_out)
{
    __shared__ float red[1024];
    __shared__ float buf[1024];
    const int b   = blockIdx.x;
    const int tid = threadIdx.x;

    const float s = scores[b * SS + tid];
    red[tid] = s;
    __syncthreads();
    for (int off = 512; off > 0; off >>= 1) {
        if (tid < off) red[tid] = fmaxf(red[tid], red[tid + off]);
        __syncthreads();
    }
    const float m = red[0];
    __syncthreads();

    const float e = expf(s - m);
    e_out[b * SS + tid] = e;

    buf[tid] = e;
    __syncthreads();
    for (int off = 1; off < 1024; off <<= 1) {
        float val = buf[tid];
        if (tid >= off) val += buf[tid - off];
        __syncthreads();
        buf[tid] = val;
        __syncthreads();
    }
    const float P = buf[tid];
    const float Z = buf[1023];

    const int type = pt[b];
    float iv;
    if (type == 0)        iv = 1.f / (P * (float)(tid + 1));
    else if (type == 1)   iv = 1.f / ((Z - P + e) * (float)(SS - tid));
    else                  iv = 1.f / ((Z - e) * (float)(SS - 1));
    iv_out[b * SS + tid] = iv;
}

// ---------------------------------------------------------------------------
// Kernel 3: pooled output via per-type scan. 1024 thr (16 waves), wave owns 64 l's.
// grid: B * (D/64) = 256 blocks -> 2 blocks/CU, full 2048-thread occupancy.
// ---------------------------------------------------------------------------
__global__ __launch_bounds__(1024) void pool_kernel(
    const float* __restrict__ hidden, const float* __restrict__ e_in,
    const float* __restrict__ iv_in, const int* __restrict__ pt,
    float* __restrict__ out)
{
    __shared__ float e_s[1024];
    __shared__ float iv_s[1024];
    __shared__ float seg[16][64];

    const int tid  = threadIdx.x;
    const int wave = tid >> 6;
    const int lane = tid & 63;
    const int b    = blockIdx.x >> 4;
    const int d    = (blockIdx.x & 15) * 64 + lane;

    e_s [tid] = e_in [b * SS + tid];
    iv_s[tid] = iv_in[b * SS + tid];
    __syncthreads();

    const float* hb = hidden + (size_t)b * SS * DD + d;
    float*       ob = out    + (size_t)b * SS * DD + d;
    const int l0 = wave * 64;

    float a0 = 0.f, a1 = 0.f, a2 = 0.f, a3 = 0.f;
    #pragma unroll
    for (int i = 0; i < 64; i += 4) {
        const int j = l0 + i;
        a0 += e_s[j + 0] * hb[(size_t)(j + 0) * DD];
        a1 += e_s[j + 1] * hb[(size_t)(j + 1) * DD];
        a2 += e_s[j + 2] * hb[(size_t)(j + 2) * DD];
        a3 += e_s[j + 3] * hb[(size_t)(j + 3) * DD];
    }
    seg[wave][lane] = (a0 + a1) + (a2 + a3);
    __syncthreads();

    const int type = pt[b];
    if (type == 0) {                       // prefix: forward scan
        float run = 0.f;
        for (int w = 0; w < wave; ++w) run += seg[w][lane];
        #pragma unroll 4
        for (int i = 0; i < 64; ++i) {
            const int j = l0 + i;
            run += e_s[j] * hb[(size_t)j * DD];
            ob[(size_t)j * DD] = run * iv_s[j];
        }
    } else if (type == 1) {                // postfix: backward scan
        float run = 0.f;
        for (int w = wave + 1; w < 16; ++w) run += seg[w][lane];
        #pragma unroll 4
        for (int i = 63; i >= 0; --i) {
            const int j = l0 + i;
            run += e_s[j] * hb[(size_t)j * DD];
            ob[(size_t)j * DD] = run * iv_s[j];
        }
    } else {                               // cloze: total minus self
        float T = 0.f;
        #pragma unroll
        for (int w = 0; w < 16; ++w) T += seg[w][lane];
        #pragma unroll 4
        for (int i = 0; i < 64; ++i) {
            const int j = l0 + i;
            ob[(size_t)j * DD] = (T - e_s[j] * hb[(size_t)j * DD]) * iv_s[j];
        }
    }
}

// ---------------------------------------------------------------------------
extern "C" void kernel_launch(void* const* d_in, const int* in_sizes, int n_in,
                              void* d_out, int out_size, void* d_ws, size_t ws_size,
                              hipStream_t stream) {
    const float* hidden = (const float*)d_in[0];
    const float* W1     = (const float*)d_in[1];
    const float* b1     = (const float*)d_in[2];
    const float* v      = (const float*)d_in[3];
    const int*   pt     = (const int*)  d_in[4];
    float* out = (float*)d_out;

    float* ws     = (float*)d_ws;
    float* scores = ws;                         // 16384 f32
    float* e      = ws + BB * SS;               // 16384 f32
    float* iv     = ws + 2 * BB * SS;           // 16384 f32
    short* W1f    = (short*)(ws + 3 * BB * SS); // 262144 bf16 (512 KiB)

    w1cvt_kernel      <<<128, 256, 0, stream>>>(W1, W1f);
    scores_mfma_kernel<<<(BB * SS) / 32, 256, 0, stream>>>(hidden, W1f, b1, v, scores);
    prep_kernel       <<<BB, 1024, 0, stream>>>(scores, pt, e, iv);
    pool_kernel       <<<BB * (DD / 64), 1024, 0, stream>>>(hidden, e, iv, pt, out);
}

// Round 6
// 179.748 us; speedup vs baseline: 1.5087x; 1.0289x over previous
//
#include <hip/hip_runtime.h>
#include <hip/hip_bf16.h>
#include <math.h>

#define SS 1024
#define DD 1024
#define AA 256
#define BB 16

typedef short short8 __attribute__((ext_vector_type(8)));
typedef float f32x4 __attribute__((ext_vector_type(4)));

static __device__ __forceinline__ short f2bf(float f) {
    __hip_bfloat16 h = __float2bfloat16(f);   // RNE, compiles to v_cvt_pk when paired
    union { __hip_bfloat16 h; short s; } u; u.h = h;
    return u.s;
}

// ---------------------------------------------------------------------------
// Kernel 0: pack W1 (f32 [K=1024][N=256]) into bf16 MFMA-fragment order:
//   W1f[((kb*16 + nb)*64 + l)*8 + j] = bf16( W1[kb*32 + (l>>4)*8 + j][nb*16 + (l&15)] )
// A fragments use the same k-permutation, so any bijective k-order is valid.
// ---------------------------------------------------------------------------
__global__ __launch_bounds__(256) void w1cvt_kernel(
    const float* __restrict__ W1, short* __restrict__ W1f)
{
    const int g  = blockIdx.x * 256 + threadIdx.x;   // 0..32767
    const int l  = g & 63;
    const int nb = (g >> 6) & 15;
    const int kb = g >> 10;
    const int k0 = kb * 32 + ((l >> 4) << 3);
    const int n  = nb * 16 + (l & 15);
    short8 o;
    #pragma unroll
    for (int j = 0; j < 8; ++j) o[j] = f2bf(W1[(size_t)(k0 + j) * AA + n]);
    *reinterpret_cast<short8*>(&W1f[(size_t)g * 8]) = o;
}

// ---------------------------------------------------------------------------
// Kernel 1: scores[b,s] = tanh(hidden @ W1 + b1) . v   via bf16 MFMA.
// Barrier-free K-loop: grid 16384/16 = 1024 blocks, 256 thr (4 waves).
// Block = 16 rows; wave w owns cols [64w, 64w+64) (nb 4w..4w+3).
// A-fragment loaded directly from global (same 32B per lane for all 4 waves
// of a block -> L1 hits); B streams from L2-resident packed W1f.
// ---------------------------------------------------------------------------
__global__ __launch_bounds__(256) void scores_mfma_kernel(
    const float* __restrict__ hidden, const short* __restrict__ W1f,
    const float* __restrict__ b1, const float* __restrict__ v,
    float* __restrict__ scores)
{
    __shared__ float red[4][16];

    const int tid = threadIdx.x;
    const int w   = tid >> 6;
    const int l   = tid & 63;
    const int row0 = blockIdx.x * 16;

    // lane l reads A[row = l&15][k = kb*32 + (l>>4)*8 + j], j=0..7
    const float*  ap = hidden + (size_t)(row0 + (l & 15)) * DD + ((l >> 4) << 3);
    const short8* bp = reinterpret_cast<const short8*>(W1f) + (size_t)(w * 4) * 64 + l;

    f32x4 acc[4];
    #pragma unroll
    for (int nb = 0; nb < 4; ++nb)
        #pragma unroll
        for (int r = 0; r < 4; ++r) acc[nb][r] = 0.f;

    #pragma unroll 2
    for (int kb = 0; kb < 32; ++kb) {
        const float4 av0 = *reinterpret_cast<const float4*>(ap + kb * 32);
        const float4 av1 = *reinterpret_cast<const float4*>(ap + kb * 32 + 4);
        short8 a;
        a[0] = f2bf(av0.x); a[1] = f2bf(av0.y); a[2] = f2bf(av0.z); a[3] = f2bf(av0.w);
        a[4] = f2bf(av1.x); a[5] = f2bf(av1.y); a[6] = f2bf(av1.z); a[7] = f2bf(av1.w);
        const short8* bkp = bp + (size_t)kb * 16 * 64;
        #pragma unroll
        for (int nb = 0; nb < 4; ++nb)
            acc[nb] = __builtin_amdgcn_mfma_f32_16x16x32_bf16(a, bkp[nb * 64], acc[nb], 0, 0, 0);
    }

    // epilogue: rowsum over this wave's 64 cols of tanh(x + b1) * v
    float b1l[4], vl[4];
    #pragma unroll
    for (int nb = 0; nb < 4; ++nb) {
        const int col = w * 64 + nb * 16 + (l & 15);
        b1l[nb] = b1[col];
        vl[nb]  = v[col];
    }
    #pragma unroll
    for (int r = 0; r < 4; ++r) {
        float s = tanhf(acc[0][r] + b1l[0]) * vl[0]
                + tanhf(acc[1][r] + b1l[1]) * vl[1]
                + tanhf(acc[2][r] + b1l[2]) * vl[2]
                + tanhf(acc[3][r] + b1l[3]) * vl[3];
        s += __shfl_xor(s, 1, 64);
        s += __shfl_xor(s, 2, 64);
        s += __shfl_xor(s, 4, 64);
        s += __shfl_xor(s, 8, 64);
        if ((l & 15) == 0) red[w][((l >> 4) << 2) + r] = s;   // row = (l>>4)*4 + r
    }
    __syncthreads();
    if (tid < 16)
        scores[row0 + tid] = red[0][tid] + red[1][tid] + red[2][tid] + red[3][tid];
}

// ---------------------------------------------------------------------------
// Kernel 2: fused softmax-prep + pooled-output scan.
// grid: B * (D/64) = 256 blocks, 1024 thr (16 waves). Wave owns 64 l's, lane one d.
// Prep (max, exp, prefix-scan, per-type inverse scale) redone per block in
// LDS/registers via wave shuffles (~5 barriers) — removes a kernel launch.
// ---------------------------------------------------------------------------
__global__ __launch_bounds__(1024) void pool_kernel(
    const float* __restrict__ hidden, const float* __restrict__ scores,
    const int* __restrict__ pt, float* __restrict__ out)
{
    __shared__ float e_s[1024];
    __shared__ float iv_s[1024];
    __shared__ float seg[16][64];
    __shared__ float wmax[16];
    __shared__ float wsum[16];

    const int tid  = threadIdx.x;
    const int wave = tid >> 6;
    const int lane = tid & 63;
    const int b    = blockIdx.x >> 4;
    const int d    = (blockIdx.x & 15) * 64 + lane;

    // ---- prep: batch max ----
    const float s = scores[b * SS + tid];
    float mx = s;
    #pragma unroll
    for (int off = 32; off > 0; off >>= 1) mx = fmaxf(mx, __shfl_xor(mx, off, 64));
    if (lane == 0) wmax[wave] = mx;
    __syncthreads();
    float m = wmax[0];
    #pragma unroll
    for (int i = 1; i < 16; ++i) m = fmaxf(m, wmax[i]);

    // ---- prep: exp + inclusive prefix scan ----
    const float e = expf(s - m);
    float ps = e;
    #pragma unroll
    for (int off = 1; off < 64; off <<= 1) {
        const float t = __shfl_up(ps, off, 64);
        if (lane >= off) ps += t;
    }
    if (lane == 63) wsum[wave] = ps;
    __syncthreads();
    float pre = 0.f, Z = 0.f;
    #pragma unroll
    for (int i = 0; i < 16; ++i) {
        const float t = wsum[i];
        if (i < wave) pre += t;
        Z += t;
    }
    const float P = ps + pre;   // inclusive prefix sum of e up to tid

    const int type = pt[b];
    float iv;
    if (type == 0)        iv = 1.f / (P * (float)(tid + 1));
    else if (type == 1)   iv = 1.f / ((Z - P + e) * (float)(SS - tid));
    else                  iv = 1.f / ((Z - e) * (float)(SS - 1));
    e_s[tid]  = e;
    iv_s[tid] = iv;
    __syncthreads();

    // ---- per-wave segment sums of e_l * h[l,d] ----
    const float* hb = hidden + (size_t)b * SS * DD + d;
    float*       ob = out    + (size_t)b * SS * DD + d;
    const int l0 = wave * 64;

    float a0 = 0.f, a1 = 0.f, a2 = 0.f, a3 = 0.f;
    #pragma unroll
    for (int i = 0; i < 64; i += 4) {
        const int j = l0 + i;
        a0 += e_s[j + 0] * hb[(size_t)(j + 0) * DD];
        a1 += e_s[j + 1] * hb[(size_t)(j + 1) * DD];
        a2 += e_s[j + 2] * hb[(size_t)(j + 2) * DD];
        a3 += e_s[j + 3] * hb[(size_t)(j + 3) * DD];
    }
    seg[wave][lane] = (a0 + a1) + (a2 + a3);
    __syncthreads();

    // ---- per-type output pass ----
    if (type == 0) {                       // prefix: forward scan
        float run = 0.f;
        for (int w2 = 0; w2 < wave; ++w2) run += seg[w2][lane];
        #pragma unroll 4
        for (int i = 0; i < 64; ++i) {
            const int j = l0 + i;
            run += e_s[j] * hb[(size_t)j * DD];
            __builtin_nontemporal_store(run * iv_s[j], &ob[(size_t)j * DD]);
        }
    } else if (type == 1) {                // postfix: backward scan
        float run = 0.f;
        for (int w2 = wave + 1; w2 < 16; ++w2) run += seg[w2][lane];
        #pragma unroll 4
        for (int i = 63; i >= 0; --i) {
            const int j = l0 + i;
            run += e_s[j] * hb[(size_t)j * DD];
            __builtin_nontemporal_store(run * iv_s[j], &ob[(size_t)j * DD]);
        }
    } else {                               // cloze: total minus self
        float T = 0.f;
        #pragma unroll
        for (int w2 = 0; w2 < 16; ++w2) T += seg[w2][lane];
        #pragma unroll 4
        for (int i = 0; i < 64; ++i) {
            const int j = l0 + i;
            __builtin_nontemporal_store((T - e_s[j] * hb[(size_t)j * DD]) * iv_s[j],
                                        &ob[(size_t)j * DD]);
        }
    }
}

// ---------------------------------------------------------------------------
extern "C" void kernel_launch(void* const* d_in, const int* in_sizes, int n_in,
                              void* d_out, int out_size, void* d_ws, size_t ws_size,
                              hipStream_t stream) {
    const float* hidden = (const float*)d_in[0];
    const float* W1     = (const float*)d_in[1];
    const float* b1     = (const float*)d_in[2];
    const float* v      = (const float*)d_in[3];
    const int*   pt     = (const int*)  d_in[4];
    float* out = (float*)d_out;

    float* ws     = (float*)d_ws;
    float* scores = ws;                     // 16384 f32
    short* W1f    = (short*)(ws + BB * SS); // 262144 bf16 (512 KiB)

    w1cvt_kernel      <<<128, 256, 0, stream>>>(W1, W1f);
    scores_mfma_kernel<<<(BB * SS) / 16, 256, 0, stream>>>(hidden, W1f, b1, v, scores);
    pool_kernel       <<<BB * (DD / 64), 1024, 0, stream>>>(hidden, scores, pt, out);
}